// Round 5
// baseline (371.638 us; speedup 1.0000x reference)
//
#include <hip/hip_runtime.h>
#include <hip/hip_bf16.h>
#include <cstdint>
#include <cstddef>

// ---------------------------------------------------------------------------
// bi_Mlp (fp32 I/O): out = binlin2( clip(gelu(binlin1(x))) )
// R10 -> R11:
//  * R10 goff-hoist REVERTED (VALUBusy rose 40->53 with dur flat -> not
//    issue-bound; hoist cost +4 VGPR and +2.5% dur).
//  * Occupancy experiment: MfmaUtil pinned at 25% in every 4-wave 128^2
//    variant; same structure hits 37% (m97) at ~12 waves/CU. Our 26%
//    occupancy = 2 blocks/CU: 80 VGPR + 64 AGPR = 144 total lands in the
//    <=256 reg tier -> 2 waves/SIMD (HW tiers {64,128,256}, unified file).
//    Fix: __launch_bounds__(256,4) + live-range diet -- af[4] cached, bfv
//    STREAMED per-j (drops 12 live VGPRs) -> target 64 VGPR + 64 AGPR = 128
//    total -> 4 waves/SIMD tier -> 4 blocks/CU.
//  * Everything else byte-identical to R9: 128^2 tile, K-step 64, 4 waves,
//    XOR-swizzled LDS (0 conflicts), XCD banding, grid-stride prep.
//  * Prediction: Occupancy 26->~50, MfmaUtil 25->35-42, G1/G2 99->72-82us.
//    Falsifier: occupancy up but dur flat -> pivot to 4x8 acc per wave.
// ---------------------------------------------------------------------------

typedef __bf16 bf16x8 __attribute__((ext_vector_type(8)));
typedef __bf16 bf16x4 __attribute__((ext_vector_type(4)));
typedef float floatx4 __attribute__((ext_vector_type(4)));

__device__ __forceinline__ void async_load16(const void* g, void* l) {
    __builtin_amdgcn_global_load_lds(
        (const __attribute__((address_space(1))) void*)g,
        (__attribute__((address_space(3))) void*)l,
        16, 0, 0);
}

// Grid-stride prep: blocks [0, NBX) convert x fp32->bf16 (8 elem/thread/iter);
// blocks [NBX, NBX+960): one wave per weight row (w1 rows 0..3071, then w2).
__global__ __launch_bounds__(256) void prep_all(
    const float* __restrict__ x,
    const float* __restrict__ w1,
    const float* __restrict__ w2,
    __hip_bfloat16* __restrict__ xb,
    __hip_bfloat16* __restrict__ sgn1, float* __restrict__ alpha1,
    __hip_bfloat16* __restrict__ sgn2, float* __restrict__ alpha2,
    int nx8, int NBX)
{
    const int b = blockIdx.x;
    const int tid = threadIdx.x;
    if (b < NBX) {
        const float4* xv = (const float4*)x;
        bf16x8* xo = (bf16x8*)xb;
        const int stride = NBX * 256;
        for (int i = b * 256 + tid; i < nx8; i += stride) {
            float4 a = xv[2 * i];
            float4 c = xv[2 * i + 1];
            bf16x8 o;
            o[0] = (__bf16)a.x; o[1] = (__bf16)a.y;
            o[2] = (__bf16)a.z; o[3] = (__bf16)a.w;
            o[4] = (__bf16)c.x; o[5] = (__bf16)c.y;
            o[6] = (__bf16)c.z; o[7] = (__bf16)c.w;
            xo[i] = o;
        }
        return;
    }
    const int lane = tid & 63;
    const int wv = tid >> 6;
    const int wr = (b - NBX) * 4 + wv;          // 0..3839
    const float* w; __hip_bfloat16* sgn; float* alpha; int cols4; int row;
    if (wr < 3072) {
        w = w1; sgn = sgn1; alpha = alpha1; cols4 = 192; row = wr;
    } else {
        w = w2; sgn = sgn2; alpha = alpha2; cols4 = 768; row = wr - 3072;
    }
    const float4* wrp = (const float4*)w + (size_t)row * cols4;
    bf16x4* sr = (bf16x4*)sgn + (size_t)row * cols4;
    float s = 0.0f;
    for (int c = lane; c < cols4; c += 64) {
        float4 v = wrp[c];
        s += fabsf(v.x) + fabsf(v.y) + fabsf(v.z) + fabsf(v.w);
        bf16x4 o;
        o[0] = (__bf16)(v.x > 0.0f ? 1.0f : (v.x < 0.0f ? -1.0f : 0.0f));
        o[1] = (__bf16)(v.y > 0.0f ? 1.0f : (v.y < 0.0f ? -1.0f : 0.0f));
        o[2] = (__bf16)(v.z > 0.0f ? 1.0f : (v.z < 0.0f ? -1.0f : 0.0f));
        o[3] = (__bf16)(v.w > 0.0f ? 1.0f : (v.w < 0.0f ? -1.0f : 0.0f));
        sr[c] = o;
    }
    #pragma unroll
    for (int off = 32; off > 0; off >>= 1) s += __shfl_down(s, off, 64);
    if (lane == 0) alpha[row] = s / (float)(cols4 * 4);
}

__device__ __forceinline__ void store_val(__hip_bfloat16* C, size_t idx, float v) {
    C[idx] = __float2bfloat16(v);
}
__device__ __forceinline__ void store_val(float* C, size_t idx, float v) {
    C[idx] = v;
}

// C[M,N] = (A[M,K] . S[N,K]^T) * alpha[N] + bias[N]  (+ optional gelu/clip)
// 128x128 tile, K-step 64, 4 waves (2x2), 16x16x32 bf16 MFMA.
// XOR-swizzled LDS: slot s of row r holds k-chunk s^(r&7) (0 conflicts).
// 1-D grid, XCD-banded: l=(b&7)*perXcd+(b>>3); m = l/NT (band), n = l%NT.
// Register diet: af[4] cached, bfv streamed per-j; target 64V+64A=128 total
// -> 4 waves/SIMD tier.
template <bool DO_GELU, typename OutT>
__global__ __launch_bounds__(256, 4) void gemm_bin(
    const __hip_bfloat16* __restrict__ A,
    const __hip_bfloat16* __restrict__ S,
    const float* __restrict__ alpha,
    const float* __restrict__ bias,
    OutT* __restrict__ C,
    int M, int N, int K, int T, int perXcd)
{
    constexpr int TM = 128;
    constexpr int TN = 128;
    constexpr int TK = 64;

    const int b = blockIdx.x;
    const int l = (b & 7) * perXcd + (b >> 3);
    if (l >= T) return;
    const int NT = N / TN;
    const int mt = l / NT;
    const int nt = l - mt * NT;
    const int bm = mt * TM;
    const int bn = nt * TN;

    __shared__ __align__(16) __hip_bfloat16 sA[TM * TK];
    __shared__ __align__(16) __hip_bfloat16 sB[TN * TK];

    const int tid = threadIdx.x;
    const int wave = tid >> 6;
    const int lane = tid & 63;

    const int wm = (wave & 1) * 64;
    const int wn = (wave >> 1) * 64;
    const int lr = lane & 15;         // m (A) / n (B) index within 16-tile
    const int kq = lane >> 4;         // 0..3: 8-elem k-chunk within 32-step
    const int e3 = lr & 7;            // swizzle class

    // staging: lane writes LDS offset lane*16B; fetch global chunk
    // (lane&7)^(lane>>3) so slot s of row r holds chunk s^(r&7)
    const int crow = lane >> 3;
    const int ccol = ((lane & 7) ^ crow) * 8;

    floatx4 acc[4][4];
    #pragma unroll
    for (int i = 0; i < 4; i++)
        #pragma unroll
        for (int j = 0; j < 4; j++)
            #pragma unroll
            for (int r = 0; r < 4; r++)
                acc[i][j][r] = 0.0f;

    for (int k0 = 0; k0 < K; k0 += TK) {
        // --- stage A (128 rows) + B (128 rows), 16B/lane async
        #pragma unroll
        for (int t = 0; t < 8; t++) {
            const int seg = wave * 8 + t;        // wave-uniform, 0..31
            if (seg < 16) {
                const int r = seg * 8 + crow;
                int ar = bm + r;
                ar = ar < M ? ar : (M - 1);      // clamp tail rows (stores guarded)
                async_load16(A + (size_t)ar * K + (k0 + ccol), (void*)(sA + seg * 512));
            } else {
                const int r = (seg - 16) * 8 + crow;
                async_load16(S + (size_t)(bn + r) * K + (k0 + ccol),
                             (void*)(sB + (seg - 16) * 512));
            }
        }
        __syncthreads();

        // --- compute: 2 k-steps of 32; af cached, bfv streamed (reg diet)
        #pragma unroll
        for (int ks = 0; ks < 2; ks++) {
            const int slot = ((ks << 2) | kq) ^ e3;   // k-chunk kc = ks*4+kq
            bf16x8 af[4];
            #pragma unroll
            for (int i = 0; i < 4; i++)
                af[i] = *(const bf16x8*)(sA + (wm + i * 16 + lr) * TK + slot * 8);
            #pragma unroll
            for (int j = 0; j < 4; j++) {
                const bf16x8 bfv =
                    *(const bf16x8*)(sB + (wn + j * 16 + lr) * TK + slot * 8);
                #pragma unroll
                for (int i = 0; i < 4; i++)
                    acc[i][j] = __builtin_amdgcn_mfma_f32_16x16x32_bf16(
                        af[i], bfv, acc[i][j], 0, 0, 0);
            }
        }
        __syncthreads();
    }

    // --- epilogue: alpha/bias fp32, optional exact-erf gelu + clip
    float al[4], bi[4];
    #pragma unroll
    for (int j = 0; j < 4; j++) {
        const int col = bn + wn + j * 16 + lr;
        al[j] = alpha[col];
        bi[j] = bias[col];
    }
    #pragma unroll
    for (int i = 0; i < 4; i++) {
        const int row0 = bm + wm + i * 16 + kq * 4;
        #pragma unroll
        for (int r = 0; r < 4; r++) {
            const int row = row0 + r;
            if (row < M) {
                #pragma unroll
                for (int j = 0; j < 4; j++) {
                    float v = acc[i][j][r] * al[j] + bi[j];
                    if (DO_GELU) {
                        v = 0.5f * v * (1.0f + erff(v * 0.70710678118654752f));
                        v = fminf(fmaxf(v, -10.0f), 10.0f);
                    }
                    store_val(C, (size_t)row * N + (bn + wn + j * 16 + lr), v);
                }
            }
        }
    }
}

extern "C" void kernel_launch(void* const* d_in, const int* in_sizes, int n_in,
                              void* d_out, int out_size, void* d_ws, size_t ws_size,
                              hipStream_t stream) {
    const float* x  = (const float*)d_in[0];
    const float* w1 = (const float*)d_in[1];
    const float* b1 = (const float*)d_in[2];
    const float* w2 = (const float*)d_in[3];
    const float* b2 = (const float*)d_in[4];

    const int M = 64 * 197;   // 12608
    const int Cd = 768;
    const int Hd = 3072;

    // workspace layout (~106 MB total)
    char* ws = (char*)d_ws;
    __hip_bfloat16* xb   = (__hip_bfloat16*)ws;                 // [M, Cd]
    __hip_bfloat16* sgn1 = xb + (size_t)M * Cd;                 // [Hd, Cd]
    __hip_bfloat16* sgn2 = sgn1 + (size_t)Hd * Cd;              // [Cd, Hd]
    float* alpha1 = (float*)(sgn2 + (size_t)Cd * Hd);           // [Hd]
    float* alpha2 = alpha1 + Hd;                                // [Cd]
    __hip_bfloat16* hbuf = (__hip_bfloat16*)(alpha2 + Cd);      // [M, Hd]

    // prep: 1280 x-convert blocks (grid-stride) + 960 wave-per-row blocks
    const int nx8 = (M * Cd) / 8;          // 1,210,368 (exact)
    const int NBX = 1280;
    const int NBW = (3072 + 768) / 4;      // 960
    prep_all<<<NBX + NBW, 256, 0, stream>>>(
        x, w1, w2, xb, sgn1, alpha1, sgn2, alpha2, nx8, NBX);

    const int gm = (M + 127) / 128;        // 99

    // GEMM1: 24x99 = 2376 tiles; perXcd = 297 (exact)
    {
        const int T = (Hd / 128) * gm;
        const int perXcd = (T + 7) / 8;
        gemm_bin<true, __hip_bfloat16><<<perXcd * 8, 256, 0, stream>>>(
            xb, sgn1, alpha1, b1, hbuf, M, Hd, Cd, T, perXcd);
    }
    // GEMM2: 6x99 = 594 tiles; perXcd = 75, grid 600 (6 idle blocks)
    {
        const int T = (Cd / 128) * gm;
        const int perXcd = (T + 7) / 8;
        gemm_bin<false, float><<<perXcd * 8, 256, 0, stream>>>(
            hbuf, sgn2, alpha2, b2, (float*)d_out, M, Cd, Hd, T, perXcd);
    }
}

// Round 6
// 300.904 us; speedup vs baseline: 1.2351x; 1.2351x over previous
//
#include <hip/hip_runtime.h>
#include <hip/hip_bf16.h>
#include <cstdint>
#include <cstddef>

// ---------------------------------------------------------------------------
// bi_Mlp (fp32 I/O): out = binlin2( clip(gelu(binlin1(x))) )
// R11 -> R12:
//  * R11 post-mortem: __launch_bounds__(256,4) with a 64-AGPR accumulator
//    forced spills (WRITE +54MB scratch, MfmaUtil 13.9, 173us). The <=128-reg
//    tier is unreachable at per-wave 64x64. Occupancy theory untested, not
//    falsified.
//  * R12: halve per-wave work instead of squeezing regs. Tile 128x64, 4 waves
//    (2m x 2n), per-wave 64x32 -> acc[4][2] = 32 AGPR; ~24 V frags + addr
//    => ~100 total, fits <=128 tier WITH headroom -> 4 waves/SIMD ->
//    16 waves/CU from 4 independent blocks (4 barrier domains vs 2: m114
//    cross-block MFMA/stall overlap is the mechanism this structure lacked).
//  * MFMA:ds_read improves to 16:6 (was 32:16). Staging traffic x1.5 --
//    irrelevant at 19% HBM, L3-resident working set.
//  * Everything else identical to R9: XOR-swizzled LDS (0 conflicts), inline
//    staging math (R10 hoist hurt), XCD banding, grid-stride prep.
//  * Tripwires: WRITE>80MB => spilled again; occ ~50% + MfmaUtil<=30 =>
//    occupancy axis dead.
// ---------------------------------------------------------------------------

typedef __bf16 bf16x8 __attribute__((ext_vector_type(8)));
typedef __bf16 bf16x4 __attribute__((ext_vector_type(4)));
typedef float floatx4 __attribute__((ext_vector_type(4)));

__device__ __forceinline__ void async_load16(const void* g, void* l) {
    __builtin_amdgcn_global_load_lds(
        (const __attribute__((address_space(1))) void*)g,
        (__attribute__((address_space(3))) void*)l,
        16, 0, 0);
}

// Grid-stride prep: blocks [0, NBX) convert x fp32->bf16 (8 elem/thread/iter);
// blocks [NBX, NBX+960): one wave per weight row (w1 rows 0..3071, then w2).
__global__ __launch_bounds__(256) void prep_all(
    const float* __restrict__ x,
    const float* __restrict__ w1,
    const float* __restrict__ w2,
    __hip_bfloat16* __restrict__ xb,
    __hip_bfloat16* __restrict__ sgn1, float* __restrict__ alpha1,
    __hip_bfloat16* __restrict__ sgn2, float* __restrict__ alpha2,
    int nx8, int NBX)
{
    const int b = blockIdx.x;
    const int tid = threadIdx.x;
    if (b < NBX) {
        const float4* xv = (const float4*)x;
        bf16x8* xo = (bf16x8*)xb;
        const int stride = NBX * 256;
        for (int i = b * 256 + tid; i < nx8; i += stride) {
            float4 a = xv[2 * i];
            float4 c = xv[2 * i + 1];
            bf16x8 o;
            o[0] = (__bf16)a.x; o[1] = (__bf16)a.y;
            o[2] = (__bf16)a.z; o[3] = (__bf16)a.w;
            o[4] = (__bf16)c.x; o[5] = (__bf16)c.y;
            o[6] = (__bf16)c.z; o[7] = (__bf16)c.w;
            xo[i] = o;
        }
        return;
    }
    const int lane = tid & 63;
    const int wv = tid >> 6;
    const int wr = (b - NBX) * 4 + wv;          // 0..3839
    const float* w; __hip_bfloat16* sgn; float* alpha; int cols4; int row;
    if (wr < 3072) {
        w = w1; sgn = sgn1; alpha = alpha1; cols4 = 192; row = wr;
    } else {
        w = w2; sgn = sgn2; alpha = alpha2; cols4 = 768; row = wr - 3072;
    }
    const float4* wrp = (const float4*)w + (size_t)row * cols4;
    bf16x4* sr = (bf16x4*)sgn + (size_t)row * cols4;
    float s = 0.0f;
    for (int c = lane; c < cols4; c += 64) {
        float4 v = wrp[c];
        s += fabsf(v.x) + fabsf(v.y) + fabsf(v.z) + fabsf(v.w);
        bf16x4 o;
        o[0] = (__bf16)(v.x > 0.0f ? 1.0f : (v.x < 0.0f ? -1.0f : 0.0f));
        o[1] = (__bf16)(v.y > 0.0f ? 1.0f : (v.y < 0.0f ? -1.0f : 0.0f));
        o[2] = (__bf16)(v.z > 0.0f ? 1.0f : (v.z < 0.0f ? -1.0f : 0.0f));
        o[3] = (__bf16)(v.w > 0.0f ? 1.0f : (v.w < 0.0f ? -1.0f : 0.0f));
        sr[c] = o;
    }
    #pragma unroll
    for (int off = 32; off > 0; off >>= 1) s += __shfl_down(s, off, 64);
    if (lane == 0) alpha[row] = s / (float)(cols4 * 4);
}

__device__ __forceinline__ void store_val(__hip_bfloat16* C, size_t idx, float v) {
    C[idx] = __float2bfloat16(v);
}
__device__ __forceinline__ void store_val(float* C, size_t idx, float v) {
    C[idx] = v;
}

// C[M,N] = (A[M,K] . S[N,K]^T) * alpha[N] + bias[N]  (+ optional gelu/clip)
// 128x64 tile, K-step 64, 4 waves (2m x 2n), per-wave 64x32, acc[4][2]=32 AGPR.
// XOR-swizzled LDS: slot s of row r holds k-chunk s^(r&7) (0 conflicts).
// 1-D grid, XCD-banded: l=(b&7)*perXcd+(b>>3); m = l/NT (band), n = l%NT.
// Staging: 24 segs (A 0..15, B 16..23) = 6 per wave, 16B/lane async.
template <bool DO_GELU, typename OutT>
__global__ __launch_bounds__(256, 4) void gemm_bin(
    const __hip_bfloat16* __restrict__ A,
    const __hip_bfloat16* __restrict__ S,
    const float* __restrict__ alpha,
    const float* __restrict__ bias,
    OutT* __restrict__ C,
    int M, int N, int K, int T, int perXcd)
{
    constexpr int TM = 128;
    constexpr int TN = 64;
    constexpr int TK = 64;

    const int b = blockIdx.x;
    const int l = (b & 7) * perXcd + (b >> 3);
    if (l >= T) return;
    const int NT = N / TN;
    const int mt = l / NT;
    const int nt = l - mt * NT;
    const int bm = mt * TM;
    const int bn = nt * TN;

    __shared__ __align__(16) __hip_bfloat16 sA[TM * TK];   // 16 KB
    __shared__ __align__(16) __hip_bfloat16 sB[TN * TK];   // 8 KB

    const int tid = threadIdx.x;
    const int wave = tid >> 6;
    const int lane = tid & 63;

    const int wm = (wave & 1) * 64;   // wave row base within tile
    const int wn = (wave >> 1) * 32;  // wave col base within tile
    const int lr = lane & 15;         // m (A) / n (B) index within 16-tile
    const int kq = lane >> 4;         // 0..3: 8-elem k-chunk within 32-step
    const int e3 = lr & 7;            // swizzle class

    // staging: lane writes LDS offset lane*16B; fetch global chunk
    // (lane&7)^(lane>>3) so slot s of row r holds chunk s^(r&7)
    const int crow = lane >> 3;
    const int ccol = ((lane & 7) ^ crow) * 8;

    floatx4 acc[4][2];
    #pragma unroll
    for (int i = 0; i < 4; i++)
        #pragma unroll
        for (int j = 0; j < 2; j++)
            #pragma unroll
            for (int r = 0; r < 4; r++)
                acc[i][j][r] = 0.0f;

    for (int k0 = 0; k0 < K; k0 += TK) {
        // --- stage A (128 rows, segs 0..15) + B (64 rows, segs 16..23)
        #pragma unroll
        for (int t = 0; t < 6; t++) {
            const int seg = wave * 6 + t;        // wave-uniform, 0..23
            if (seg < 16) {
                const int r = seg * 8 + crow;
                int ar = bm + r;
                ar = ar < M ? ar : (M - 1);      // clamp tail rows (stores guarded)
                async_load16(A + (size_t)ar * K + (k0 + ccol), (void*)(sA + seg * 512));
            } else {
                const int r = (seg - 16) * 8 + crow;
                async_load16(S + (size_t)(bn + r) * K + (k0 + ccol),
                             (void*)(sB + (seg - 16) * 512));
            }
        }
        __syncthreads();

        // --- compute: 2 k-steps of 32, 8 MFMAs each (af[4] x bf[2])
        #pragma unroll
        for (int ks = 0; ks < 2; ks++) {
            const int slot = ((ks << 2) | kq) ^ e3;   // k-chunk kc = ks*4+kq
            bf16x8 af[4], bfv[2];
            #pragma unroll
            for (int i = 0; i < 4; i++)
                af[i] = *(const bf16x8*)(sA + (wm + i * 16 + lr) * TK + slot * 8);
            #pragma unroll
            for (int j = 0; j < 2; j++)
                bfv[j] = *(const bf16x8*)(sB + (wn + j * 16 + lr) * TK + slot * 8);
            #pragma unroll
            for (int i = 0; i < 4; i++)
                #pragma unroll
                for (int j = 0; j < 2; j++)
                    acc[i][j] = __builtin_amdgcn_mfma_f32_16x16x32_bf16(
                        af[i], bfv[j], acc[i][j], 0, 0, 0);
        }
        __syncthreads();
    }

    // --- epilogue: alpha/bias fp32, optional exact-erf gelu + clip
    float al[2], bi[2];
    #pragma unroll
    for (int j = 0; j < 2; j++) {
        const int col = bn + wn + j * 16 + lr;
        al[j] = alpha[col];
        bi[j] = bias[col];
    }
    #pragma unroll
    for (int i = 0; i < 4; i++) {
        const int row0 = bm + wm + i * 16 + kq * 4;
        #pragma unroll
        for (int r = 0; r < 4; r++) {
            const int row = row0 + r;
            if (row < M) {
                #pragma unroll
                for (int j = 0; j < 2; j++) {
                    float v = acc[i][j][r] * al[j] + bi[j];
                    if (DO_GELU) {
                        v = 0.5f * v * (1.0f + erff(v * 0.70710678118654752f));
                        v = fminf(fmaxf(v, -10.0f), 10.0f);
                    }
                    store_val(C, (size_t)row * N + (bn + wn + j * 16 + lr), v);
                }
            }
        }
    }
}

extern "C" void kernel_launch(void* const* d_in, const int* in_sizes, int n_in,
                              void* d_out, int out_size, void* d_ws, size_t ws_size,
                              hipStream_t stream) {
    const float* x  = (const float*)d_in[0];
    const float* w1 = (const float*)d_in[1];
    const float* b1 = (const float*)d_in[2];
    const float* w2 = (const float*)d_in[3];
    const float* b2 = (const float*)d_in[4];

    const int M = 64 * 197;   // 12608
    const int Cd = 768;
    const int Hd = 3072;

    // workspace layout (~106 MB total)
    char* ws = (char*)d_ws;
    __hip_bfloat16* xb   = (__hip_bfloat16*)ws;                 // [M, Cd]
    __hip_bfloat16* sgn1 = xb + (size_t)M * Cd;                 // [Hd, Cd]
    __hip_bfloat16* sgn2 = sgn1 + (size_t)Hd * Cd;              // [Cd, Hd]
    float* alpha1 = (float*)(sgn2 + (size_t)Cd * Hd);           // [Hd]
    float* alpha2 = alpha1 + Hd;                                // [Cd]
    __hip_bfloat16* hbuf = (__hip_bfloat16*)(alpha2 + Cd);      // [M, Hd]

    // prep: 1280 x-convert blocks (grid-stride) + 960 wave-per-row blocks
    const int nx8 = (M * Cd) / 8;          // 1,210,368 (exact)
    const int NBX = 1280;
    const int NBW = (3072 + 768) / 4;      // 960
    prep_all<<<NBX + NBW, 256, 0, stream>>>(
        x, w1, w2, xb, sgn1, alpha1, sgn2, alpha2, nx8, NBX);

    const int gm = (M + 127) / 128;        // 99

    // GEMM1: 48x99 = 4752 tiles; perXcd = 594 (exact)
    {
        const int T = (Hd / 64) * gm;
        const int perXcd = (T + 7) / 8;
        gemm_bin<true, __hip_bfloat16><<<perXcd * 8, 256, 0, stream>>>(
            xb, sgn1, alpha1, b1, hbuf, M, Hd, Cd, T, perXcd);
    }
    // GEMM2: 12x99 = 1188 tiles; perXcd = 149, grid 1192 (4 idle blocks)
    {
        const int T = (Cd / 64) * gm;
        const int perXcd = (T + 7) / 8;
        gemm_bin<false, float><<<perXcd * 8, 256, 0, stream>>>(
            hbuf, sgn2, alpha2, b2, (float*)d_out, M, Cd, Hd, T, perXcd);
    }
}

// Round 7
// 272.124 us; speedup vs baseline: 1.3657x; 1.1058x over previous
//
#include <hip/hip_runtime.h>
#include <hip/hip_bf16.h>
#include <cstdint>
#include <cstddef>

// ---------------------------------------------------------------------------
// bi_Mlp (fp32 I/O): out = binlin2( clip(gelu(binlin1(x))) )
// R12 -> R13:
//  * R12 post-mortem: occupancy pinned at ~25% across 140/84 total regs and
//    32/24 KB LDS -> registers/LDS are NOT the residency limiter; occupancy
//    axis abandoned (counter itself suspect, gfx94x fallback).
//  * R13: back to the proven R6 128^2 / 4-wave shape, ONE variable changed:
//    minimal 2-phase double-buffer (catalog T3 floor). LDS 2x32KB; issue
//    tile t+1's 8 global_load_lds BEFORE computing tile t; single
//    __syncthreads() per K-step (vmcnt(0) drains loads that had the whole
//    MFMA block to fly + protects buffer reuse). Barriers/K-step 2->1,
//    exposed DMA latency ~0.
//  * Everything else byte-identical to R6/R9: XOR-swizzled LDS (0 conflicts),
//    inline staging math, XCD banding, grid-stride prep.
//  * Prediction: MfmaUtil 25->31-36, G1/G2 99->80-88us, total ~225-245.
//    Falsifier: GEMMs >=95us -> dbuf neutral at this shape too -> R14 =
//    producer-consumer waves or stop + polish non-GEMM residue.
// ---------------------------------------------------------------------------

typedef __bf16 bf16x8 __attribute__((ext_vector_type(8)));
typedef __bf16 bf16x4 __attribute__((ext_vector_type(4)));
typedef float floatx4 __attribute__((ext_vector_type(4)));

__device__ __forceinline__ void async_load16(const void* g, void* l) {
    __builtin_amdgcn_global_load_lds(
        (const __attribute__((address_space(1))) void*)g,
        (__attribute__((address_space(3))) void*)l,
        16, 0, 0);
}

// Grid-stride prep: blocks [0, NBX) convert x fp32->bf16 (8 elem/thread/iter);
// blocks [NBX, NBX+960): one wave per weight row (w1 rows 0..3071, then w2).
__global__ __launch_bounds__(256) void prep_all(
    const float* __restrict__ x,
    const float* __restrict__ w1,
    const float* __restrict__ w2,
    __hip_bfloat16* __restrict__ xb,
    __hip_bfloat16* __restrict__ sgn1, float* __restrict__ alpha1,
    __hip_bfloat16* __restrict__ sgn2, float* __restrict__ alpha2,
    int nx8, int NBX)
{
    const int b = blockIdx.x;
    const int tid = threadIdx.x;
    if (b < NBX) {
        const float4* xv = (const float4*)x;
        bf16x8* xo = (bf16x8*)xb;
        const int stride = NBX * 256;
        for (int i = b * 256 + tid; i < nx8; i += stride) {
            float4 a = xv[2 * i];
            float4 c = xv[2 * i + 1];
            bf16x8 o;
            o[0] = (__bf16)a.x; o[1] = (__bf16)a.y;
            o[2] = (__bf16)a.z; o[3] = (__bf16)a.w;
            o[4] = (__bf16)c.x; o[5] = (__bf16)c.y;
            o[6] = (__bf16)c.z; o[7] = (__bf16)c.w;
            xo[i] = o;
        }
        return;
    }
    const int lane = tid & 63;
    const int wv = tid >> 6;
    const int wr = (b - NBX) * 4 + wv;          // 0..3839
    const float* w; __hip_bfloat16* sgn; float* alpha; int cols4; int row;
    if (wr < 3072) {
        w = w1; sgn = sgn1; alpha = alpha1; cols4 = 192; row = wr;
    } else {
        w = w2; sgn = sgn2; alpha = alpha2; cols4 = 768; row = wr - 3072;
    }
    const float4* wrp = (const float4*)w + (size_t)row * cols4;
    bf16x4* sr = (bf16x4*)sgn + (size_t)row * cols4;
    float s = 0.0f;
    for (int c = lane; c < cols4; c += 64) {
        float4 v = wrp[c];
        s += fabsf(v.x) + fabsf(v.y) + fabsf(v.z) + fabsf(v.w);
        bf16x4 o;
        o[0] = (__bf16)(v.x > 0.0f ? 1.0f : (v.x < 0.0f ? -1.0f : 0.0f));
        o[1] = (__bf16)(v.y > 0.0f ? 1.0f : (v.y < 0.0f ? -1.0f : 0.0f));
        o[2] = (__bf16)(v.z > 0.0f ? 1.0f : (v.z < 0.0f ? -1.0f : 0.0f));
        o[3] = (__bf16)(v.w > 0.0f ? 1.0f : (v.w < 0.0f ? -1.0f : 0.0f));
        sr[c] = o;
    }
    #pragma unroll
    for (int off = 32; off > 0; off >>= 1) s += __shfl_down(s, off, 64);
    if (lane == 0) alpha[row] = s / (float)(cols4 * 4);
}

__device__ __forceinline__ void store_val(__hip_bfloat16* C, size_t idx, float v) {
    C[idx] = __float2bfloat16(v);
}
__device__ __forceinline__ void store_val(float* C, size_t idx, float v) {
    C[idx] = v;
}

// C[M,N] = (A[M,K] . S[N,K]^T) * alpha[N] + bias[N]  (+ optional gelu/clip)
// 128x128 tile, K-step 64, 4 waves (2x2), 16x16x32 bf16 MFMA.
// XOR-swizzled LDS: slot s of row r holds k-chunk s^(r&7) (0 conflicts).
// 1-D grid, XCD-banded: l=(b&7)*perXcd+(b>>3); m = l/NT (band), n = l%NT.
// 2-phase dbuf: LDS layout [buf0 A|B][buf1 A|B], 16KB each region (64KB).
// Iter t: stage(t+1)->buf p^1 ; compute(t) from buf p ; __syncthreads ; flip.
template <bool DO_GELU, typename OutT>
__global__ __launch_bounds__(256) void gemm_bin(
    const __hip_bfloat16* __restrict__ A,
    const __hip_bfloat16* __restrict__ S,
    const float* __restrict__ alpha,
    const float* __restrict__ bias,
    OutT* __restrict__ C,
    int M, int N, int K, int T, int perXcd)
{
    constexpr int TM = 128;
    constexpr int TN = 128;
    constexpr int TK = 64;

    extern __shared__ __align__(16) __hip_bfloat16 lds[];   // 2 x 16384 elems

    const int b = blockIdx.x;
    const int l = (b & 7) * perXcd + (b >> 3);
    if (l >= T) return;
    const int NT = N / TN;
    const int mt = l / NT;
    const int nt = l - mt * NT;
    const int bm = mt * TM;
    const int bn = nt * TN;

    const int tid = threadIdx.x;
    const int wave = tid >> 6;
    const int lane = tid & 63;

    const int wm = (wave & 1) * 64;
    const int wn = (wave >> 1) * 64;
    const int lr = lane & 15;         // m (A) / n (B) index within 16-tile
    const int kq = lane >> 4;         // 0..3: 8-elem k-chunk within 32-step
    const int e3 = lr & 7;            // swizzle class

    // staging: lane writes LDS offset lane*16B; fetch global chunk
    // (lane&7)^(lane>>3) so slot s of row r holds chunk s^(r&7)
    const int crow = lane >> 3;
    const int ccol = ((lane & 7) ^ crow) * 8;

    // stage one 128x64 A-tile + 128x64 B-tile at k0 into dst (A at +0, B at +8192)
    auto STAGE = [&](int k0, __hip_bfloat16* dst) {
        #pragma unroll
        for (int t = 0; t < 8; t++) {
            const int seg = wave * 8 + t;        // wave-uniform, 0..31
            if (seg < 16) {
                const int r = seg * 8 + crow;
                int ar = bm + r;
                ar = ar < M ? ar : (M - 1);      // clamp tail rows (stores guarded)
                async_load16(A + (size_t)ar * K + (k0 + ccol),
                             (void*)(dst + seg * 512));
            } else {
                const int r = (seg - 16) * 8 + crow;
                async_load16(S + (size_t)(bn + r) * K + (k0 + ccol),
                             (void*)(dst + 8192 + (seg - 16) * 512));
            }
        }
    };

    floatx4 acc[4][4];
    #pragma unroll
    for (int i = 0; i < 4; i++)
        #pragma unroll
        for (int j = 0; j < 4; j++)
            #pragma unroll
            for (int r = 0; r < 4; r++)
                acc[i][j][r] = 0.0f;

    const int KT = K / TK;

    // prologue: tile 0 -> buf 0
    STAGE(0, lds);
    __syncthreads();

    int p = 0;
    for (int t = 0; t < KT; ++t) {
        __hip_bfloat16* cur = lds + p * 16384;
        // --- prefetch next tile into the other buffer (flies during MFMA)
        if (t + 1 < KT)
            STAGE((t + 1) * TK, lds + (p ^ 1) * 16384);

        // --- compute tile t: 2 k-steps of 32, 16 MFMAs each
        const __hip_bfloat16* cA = cur;
        const __hip_bfloat16* cB = cur + 8192;
        #pragma unroll
        for (int ks = 0; ks < 2; ks++) {
            const int slot = ((ks << 2) | kq) ^ e3;   // k-chunk kc = ks*4+kq
            bf16x8 af[4], bfv[4];
            #pragma unroll
            for (int i = 0; i < 4; i++)
                af[i] = *(const bf16x8*)(cA + (wm + i * 16 + lr) * TK + slot * 8);
            #pragma unroll
            for (int j = 0; j < 4; j++)
                bfv[j] = *(const bf16x8*)(cB + (wn + j * 16 + lr) * TK + slot * 8);
            #pragma unroll
            for (int i = 0; i < 4; i++)
                #pragma unroll
                for (int j = 0; j < 4; j++)
                    acc[i][j] = __builtin_amdgcn_mfma_f32_16x16x32_bf16(
                        af[i], bfv[j], acc[i][j], 0, 0, 0);
        }

        // single barrier: drains my prefetch DMAs (had the MFMA block to fly)
        // and guarantees all waves finished reading buf p before its reuse.
        __syncthreads();
        p ^= 1;
    }

    // --- epilogue: alpha/bias fp32, optional exact-erf gelu + clip
    float al[4], bi[4];
    #pragma unroll
    for (int j = 0; j < 4; j++) {
        const int col = bn + wn + j * 16 + lr;
        al[j] = alpha[col];
        bi[j] = bias[col];
    }
    #pragma unroll
    for (int i = 0; i < 4; i++) {
        const int row0 = bm + wm + i * 16 + kq * 4;
        #pragma unroll
        for (int r = 0; r < 4; r++) {
            const int row = row0 + r;
            if (row < M) {
                #pragma unroll
                for (int j = 0; j < 4; j++) {
                    float v = acc[i][j][r] * al[j] + bi[j];
                    if (DO_GELU) {
                        v = 0.5f * v * (1.0f + erff(v * 0.70710678118654752f));
                        v = fminf(fmaxf(v, -10.0f), 10.0f);
                    }
                    store_val(C, (size_t)row * N + (bn + wn + j * 16 + lr), v);
                }
            }
        }
    }
}

extern "C" void kernel_launch(void* const* d_in, const int* in_sizes, int n_in,
                              void* d_out, int out_size, void* d_ws, size_t ws_size,
                              hipStream_t stream) {
    const float* x  = (const float*)d_in[0];
    const float* w1 = (const float*)d_in[1];
    const float* b1 = (const float*)d_in[2];
    const float* w2 = (const float*)d_in[3];
    const float* b2 = (const float*)d_in[4];

    const int M = 64 * 197;   // 12608
    const int Cd = 768;
    const int Hd = 3072;

    // workspace layout (~106 MB total)
    char* ws = (char*)d_ws;
    __hip_bfloat16* xb   = (__hip_bfloat16*)ws;                 // [M, Cd]
    __hip_bfloat16* sgn1 = xb + (size_t)M * Cd;                 // [Hd, Cd]
    __hip_bfloat16* sgn2 = sgn1 + (size_t)Hd * Cd;              // [Cd, Hd]
    float* alpha1 = (float*)(sgn2 + (size_t)Cd * Hd);           // [Hd]
    float* alpha2 = alpha1 + Hd;                                // [Cd]
    __hip_bfloat16* hbuf = (__hip_bfloat16*)(alpha2 + Cd);      // [M, Hd]

    // prep: 1280 x-convert blocks (grid-stride) + 960 wave-per-row blocks
    const int nx8 = (M * Cd) / 8;          // 1,210,368 (exact)
    const int NBX = 1280;
    const int NBW = (3072 + 768) / 4;      // 960
    prep_all<<<NBX + NBW, 256, 0, stream>>>(
        x, w1, w2, xb, sgn1, alpha1, sgn2, alpha2, nx8, NBX);

    const int gm = (M + 127) / 128;        // 99

    // GEMM1: 24x99 = 2376 tiles; perXcd = 297 (exact)
    {
        const int T = (Hd / 128) * gm;
        const int perXcd = (T + 7) / 8;
        hipFuncSetAttribute(
            reinterpret_cast<const void*>(&gemm_bin<true, __hip_bfloat16>),
            hipFuncAttributeMaxDynamicSharedMemorySize, 65536);
        gemm_bin<true, __hip_bfloat16><<<perXcd * 8, 256, 65536, stream>>>(
            xb, sgn1, alpha1, b1, hbuf, M, Hd, Cd, T, perXcd);
    }
    // GEMM2: 6x99 = 594 tiles; perXcd = 75, grid 600 (6 idle blocks)
    {
        const int T = (Cd / 128) * gm;
        const int perXcd = (T + 7) / 8;
        hipFuncSetAttribute(
            reinterpret_cast<const void*>(&gemm_bin<false, float>),
            hipFuncAttributeMaxDynamicSharedMemorySize, 65536);
        gemm_bin<false, float><<<perXcd * 8, 256, 65536, stream>>>(
            hbuf, sgn2, alpha2, b2, (float*)d_out, M, Cd, Hd, T, perXcd);
    }
}